// Round 7
// baseline (509.489 us; speedup 1.0000x reference)
//
#include <hip/hip_runtime.h>

#define Bdim 2
#define Hdim 8
#define Sdim 2048
#define Ddim 64
#define PSTR 2056   // P row stride in shorts: +8 pad breaks 16-way bank aliasing
#define NW 8        // waves per block (512 threads)

typedef short bf16x8 __attribute__((ext_vector_type(8)));
typedef short bf16x4 __attribute__((ext_vector_type(4)));
typedef float f32x4 __attribute__((ext_vector_type(4)));

// float -> bf16 bits via hardware cvt (RNE; v_cvt_pk_bf16_f32)
static __device__ __forceinline__ short f2bf(float x) {
  return __builtin_bit_cast(short, (__bf16)x);
}
static __device__ __forceinline__ float bf2f(short x) {
  unsigned u = ((unsigned)(unsigned short)x) << 16;
  return __builtin_bit_cast(float, u);
}
static __device__ __forceinline__ bf16x8 pack8(float4 a, float4 b, float s) {
  bf16x8 r;
  r[0] = f2bf(a.x * s); r[1] = f2bf(a.y * s);
  r[2] = f2bf(a.z * s); r[3] = f2bf(a.w * s);
  r[4] = f2bf(b.x * s); r[5] = f2bf(b.y * s);
  r[6] = f2bf(b.z * s); r[7] = f2bf(b.w * s);
  return r;
}

// ---------- pre-pass 1: K f32 -> bf16, same [b][h][t][d] layout ----------
__global__ __launch_bounds__(256) void cvt_k(const float* __restrict__ kp,
                                             short* __restrict__ kb) {
  size_t i = ((size_t)blockIdx.x * 256 + threadIdx.x) * 8;
  float4 x0 = *(const float4*)(kp + i);
  float4 x1 = *(const float4*)(kp + i + 4);
  bf16x8 r = pack8(x0, x1, 1.0f);
  *(bf16x8*)(kb + i) = r;
}

// ---------- pre-pass 2: V f32 [bh][t][d] -> bf16 [bh][d][t] ----------
__global__ __launch_bounds__(256) void tr_v(const float* __restrict__ vp,
                                            short* __restrict__ vt) {
  __shared__ float tile[64][65];
  const int bh = blockIdx.x >> 5;          // 0..15
  const int t0 = (blockIdx.x & 31) << 6;   // 0..2047 step 64
  const float* src = vp + ((size_t)bh * Sdim + t0) * Ddim;
  {
    const int tl = threadIdx.x >> 2;       // 0..63
    const int dg = threadIdx.x & 3;        // 0..3
#pragma unroll
    for (int q = 0; q < 4; ++q) {
      float4 x = *(const float4*)(src + tl * Ddim + dg * 16 + q * 4);
      tile[tl][dg * 16 + q * 4 + 0] = x.x;
      tile[tl][dg * 16 + q * 4 + 1] = x.y;
      tile[tl][dg * 16 + q * 4 + 2] = x.z;
      tile[tl][dg * 16 + q * 4 + 3] = x.w;
    }
  }
  __syncthreads();
  {
    const int d  = threadIdx.x >> 2;       // 0..63
    const int tg = threadIdx.x & 3;        // 16-t chunk
    short* dst = vt + ((size_t)bh * Ddim + d) * Sdim + t0 + tg * 16;
    bf16x8 o0, o1;
#pragma unroll
    for (int j = 0; j < 8; ++j) o0[j] = f2bf(tile[tg * 16 + j][d]);
#pragma unroll
    for (int j = 0; j < 8; ++j) o1[j] = f2bf(tile[tg * 16 + 8 + j][d]);
    *(bf16x8*)(dst) = o0;
    *(bf16x8*)(dst + 8) = o1;
  }
}

// ---------- pre-pass 3: cov+mask -> bf16 covm[(b*128+qt)][col][16 rows] ----------
// covm = bf16(mask ? cov : -1e9). Masked: w_cov*(-1e9-ish) -> expf -> 0.0f.
__global__ __launch_bounds__(256) void cvt_cov(const float* __restrict__ covp,
                                               const int* __restrict__ maskp,
                                               short* __restrict__ cm) {
  const int pair  = blockIdx.x >> 3;            // 0..255 = b*128+qt
  const int chunk = blockIdx.x & 7;
  const int col   = chunk * 256 + threadIdx.x;
  const size_t rowbase = (size_t)pair * 16;     // == (b*Sdim + qt*16)
  bf16x8 o0, o1;
#pragma unroll
  for (int r = 0; r < 8; ++r) {
    float c = covp[(rowbase + r) * Sdim + col];
    int   m = maskp[(rowbase + r) * Sdim + col];
    o0[r] = f2bf(m ? c : -1e9f);
  }
#pragma unroll
  for (int r = 0; r < 8; ++r) {
    float c = covp[(rowbase + 8 + r) * Sdim + col];
    int   m = maskp[(rowbase + 8 + r) * Sdim + col];
    o1[r] = f2bf(m ? c : -1e9f);
  }
  short* dst = cm + ((size_t)pair * Sdim + col) * 16;
  *(bf16x8*)(dst) = o0;
  *(bf16x8*)(dst + 8) = o1;
}

// ---------- main kernel ----------
// Fully-unrolled 8-body pipeline per wave, stage = [loads(i+1..i+2); BODY(i)]
// followed by sched_barrier(0). Round-6 lesson: without the fence the
// compiler sinks the prefetch loads to their uses (VGPR_Count=64 proved it),
// deleting the pipeline. The fence stops loads sinking past their stage while
// still letting them interleave upward into the preceding BODY's VALU.
#define SBAR __builtin_amdgcn_sched_barrier(0)

#define DECL_K(S) bf16x8 k0a##S, k0b##S, k1a##S, k1b##S;
#define DECL_V(S) bf16x8 v0##S, v1##S, v2##S, v3##S;
#define DECL_C(S) bf16x4 ca##S, cb##S;

#define LK(S, T0) {                                                            \
    const int _t = (T0);                                                       \
    k0a##S = *(const bf16x8*)(kbh + (((size_t)(_t + l15)) << 6) + (quad << 3));        \
    k0b##S = *(const bf16x8*)(kbh + (((size_t)(_t + l15)) << 6) + (quad << 3) + 32);   \
    k1a##S = *(const bf16x8*)(kbh + (((size_t)(_t + 16 + l15)) << 6) + (quad << 3));      \
    k1b##S = *(const bf16x8*)(kbh + (((size_t)(_t + 16 + l15)) << 6) + (quad << 3) + 32); \
  }

#define LV(S, T0) {                                                            \
    const int _t = (T0);                                                       \
    v0##S = *(const bf16x8*)(vtb + (((size_t)(l15))      << 11) + _t + (quad << 3)); \
    v1##S = *(const bf16x8*)(vtb + (((size_t)(16 + l15)) << 11) + _t + (quad << 3)); \
    v2##S = *(const bf16x8*)(vtb + (((size_t)(32 + l15)) << 11) + _t + (quad << 3)); \
    v3##S = *(const bf16x8*)(vtb + (((size_t)(48 + l15)) << 11) + _t + (quad << 3)); \
  }

#define LC(S, T0) {                                                            \
    const int _t = (T0);                                                       \
    ca##S = *(const bf16x4*)(cmb + (((size_t)(_t + l15)) << 4) + (quad << 2));      \
    cb##S = *(const bf16x4*)(cmb + (((size_t)(_t + 16 + l15)) << 4) + (quad << 2)); \
  }

#define BODY(KS, VS, CS, T0) {                                                 \
    f32x4 a0 = {0.f, 0.f, 0.f, 0.f}, a1 = {0.f, 0.f, 0.f, 0.f};               \
    a0 = __builtin_amdgcn_mfma_f32_16x16x32_bf16(aq0, k0a##KS, a0, 0, 0, 0);   \
    a0 = __builtin_amdgcn_mfma_f32_16x16x32_bf16(aq1, k0b##KS, a0, 0, 0, 0);   \
    a1 = __builtin_amdgcn_mfma_f32_16x16x32_bf16(aq0, k1a##KS, a1, 0, 0, 0);   \
    a1 = __builtin_amdgcn_mfma_f32_16x16x32_bf16(aq1, k1b##KS, a1, 0, 0, 0);   \
    const int col0 = (T0) + l15;                                               \
    const int row0 = quad * 4;                                                 \
    _Pragma("unroll") for (int r = 0; r < 4; ++r) {                            \
      float p0 = __expf(a0[r] + w_cov * bf2f(ca##CS[r]));                      \
      float p1 = __expf(a1[r] + w_cov * bf2f(cb##CS[r]));                      \
      lsum[r] += p0 + p1;                                                      \
      Pl[row0 + r][col0]      = f2bf(p0);                                      \
      Pl[row0 + r][col0 + 16] = f2bf(p1);                                      \
    }                                                                          \
    bf16x8 pa = *(const bf16x8*)&Pl[l15][(T0) + quad * 8];                     \
    oacc0 = __builtin_amdgcn_mfma_f32_16x16x32_bf16(pa, v0##VS, oacc0, 0, 0, 0); \
    oacc1 = __builtin_amdgcn_mfma_f32_16x16x32_bf16(pa, v1##VS, oacc1, 0, 0, 0); \
    oacc2 = __builtin_amdgcn_mfma_f32_16x16x32_bf16(pa, v2##VS, oacc2, 0, 0, 0); \
    oacc3 = __builtin_amdgcn_mfma_f32_16x16x32_bf16(pa, v3##VS, oacc3, 0, 0, 0); \
  }

__global__ __launch_bounds__(512, 4) void fused_attn(
    const float* __restrict__ qp, const short* __restrict__ kbp,
    const short* __restrict__ vtp, const short* __restrict__ cmp,
    const float* __restrict__ lamp,
    float* __restrict__ outO, float* __restrict__ outA)
{
  __shared__ __align__(16) short Pl[16][PSTR];  // 65792 B -> 2 blocks/CU
  __shared__ float Ls[NW][16];
  __shared__ float Lrow[16];

  const int tid  = threadIdx.x;
  const int wv   = tid >> 6;
  const int lane = tid & 63;
  const int quad = lane >> 4;
  const int l15  = lane & 15;

  // h in low bits: head h pins to XCD h; K/V per XCD ~1 MB -> L2-resident.
  const int bid = blockIdx.x;
  const int h  = bid & 7;
  const int qt = (bid >> 3) & 127;
  const int b  = bid >> 10;

  const float lam   = lamp[h];
  const float w_qk  = 1.0f / (lam + 1.0f);
  const float w_cov = lam / (lam + 1.0f);
  const float qscale = w_qk * 0.125f;   // fold 1/TEMPERATURE and w_qk into Q

  const int q0 = qt * 16;
  const int bh = b * Hdim + h;

  const float* qbase = qp + ((size_t)bh * Sdim + q0) * Ddim;
  const short* kbh   = kbp + (size_t)bh * Sdim * Ddim;
  const short* vtb   = vtp + (size_t)bh * Ddim * Sdim;
  const short* cmb   = cmp + ((size_t)(b * 128 + qt)) * Sdim * 16;
  float* oA = outA + ((size_t)bh * Sdim + q0) * (size_t)Sdim;
  float* oO = outO + ((size_t)bh * Sdim + q0) * Ddim;

  // Q A-frag (16 rows x 64 k), pre-scaled: A[m=l15][k=quad*8+j]
  bf16x8 aq0, aq1;
  {
    const float* qr = qbase + l15 * Ddim + quad * 8;
    float4 x0 = *(const float4*)(qr);
    float4 x1 = *(const float4*)(qr + 4);
    aq0 = pack8(x0, x1, qscale);
    float4 y0 = *(const float4*)(qr + 32);
    float4 y1 = *(const float4*)(qr + 36);
    aq1 = pack8(y0, y1, qscale);
  }

  const int t = wv * (Sdim / NW);   // this wave's 256-col slice

  float lsum[4] = {0.f, 0.f, 0.f, 0.f};
  f32x4 oacc0 = {0.f, 0.f, 0.f, 0.f}, oacc1 = {0.f, 0.f, 0.f, 0.f};
  f32x4 oacc2 = {0.f, 0.f, 0.f, 0.f}, oacc3 = {0.f, 0.f, 0.f, 0.f};

  DECL_K(A) DECL_K(B)
  DECL_V(X) DECL_V(Y)
  DECL_C(c0) DECL_C(c1) DECL_C(c2)

  // prologue
  LK(A, t)         LV(X, t)         LC(c0, t)        LC(c1, t + 32)
  SBAR;
  // 8-body pipeline; every stage ends in a scheduling fence
  LK(B, t + 32)    LV(Y, t + 32)    LC(c2, t + 64)   BODY(A, X, c0, t)        SBAR;
  LK(A, t + 64)    LV(X, t + 64)    LC(c0, t + 96)   BODY(B, Y, c1, t + 32)   SBAR;
  LK(B, t + 96)    LV(Y, t + 96)    LC(c1, t + 128)  BODY(A, X, c2, t + 64)   SBAR;
  LK(A, t + 128)   LV(X, t + 128)   LC(c2, t + 160)  BODY(B, Y, c0, t + 96)   SBAR;
  LK(B, t + 160)   LV(Y, t + 160)   LC(c0, t + 192)  BODY(A, X, c1, t + 128)  SBAR;
  LK(A, t + 192)   LV(X, t + 192)   LC(c1, t + 224)  BODY(B, Y, c2, t + 160)  SBAR;
  LK(B, t + 224)   LV(Y, t + 224)                    BODY(A, X, c0, t + 192)  SBAR;
                                                     BODY(B, Y, c1, t + 224)

  // ---- cross-wave row-sum reduction ----
#pragma unroll
  for (int r = 0; r < 4; ++r) {
    float s = lsum[r];
    s += __shfl_xor(s, 1, 16);
    s += __shfl_xor(s, 2, 16);
    s += __shfl_xor(s, 4, 16);
    s += __shfl_xor(s, 8, 16);
    if (l15 == 0) Ls[wv][quad * 4 + r] = s;
  }
  __syncthreads();
  if (tid < 16) {
    float s = 0.f;
#pragma unroll
    for (int w2 = 0; w2 < NW; ++w2) s += Ls[w2][tid];
    Lrow[tid] = 1.0f / s;
  }
  __syncthreads();

  // ---- normalize + write attn (each wave: its own 256-col slice, all 16 rows) ----
#pragma unroll 1
  for (int row = 0; row < 16; ++row) {
    const float rinv = Lrow[row];
    float* orow = oA + (size_t)row * Sdim;
    const int c0 = t + lane * 4;
    bf16x4 pv = *(const bf16x4*)&Pl[row][c0];
    f32x4 o;
    o[0] = bf2f(pv[0]) * rinv;
    o[1] = bf2f(pv[1]) * rinv;
    o[2] = bf2f(pv[2]) * rinv;
    o[3] = bf2f(pv[3]) * rinv;
    __builtin_nontemporal_store(o, (f32x4*)&orow[c0]);
  }
  __syncthreads();   // all P reads done; safe to alias

  // ---- O reduction across waves (alias P region), scale by 1/l, store ----
  float* Ored = (float*)&Pl[0][0];   // [NW][64][16] f32 = 32 KB, fits in P alias
#pragma unroll
  for (int r = 0; r < 4; ++r) {
    Ored[((wv * 64 + lane) * 16) + 0  + r] = oacc0[r];
    Ored[((wv * 64 + lane) * 16) + 4  + r] = oacc1[r];
    Ored[((wv * 64 + lane) * 16) + 8  + r] = oacc2[r];
    Ored[((wv * 64 + lane) * 16) + 12 + r] = oacc3[r];
  }
  __syncthreads();
  if (wv < 4) {
#pragma unroll
    for (int r = 0; r < 4; ++r) {
      float s = 0.f;
#pragma unroll
      for (int w2 = 0; w2 < NW; ++w2)
        s += Ored[((w2 * 64 + lane) * 16) + wv * 4 + r];
      const int row = quad * 4 + r;
      __builtin_nontemporal_store(s * Lrow[row], &oO[row * Ddim + wv * 16 + l15]);
    }
  }
}

extern "C" void kernel_launch(void* const* d_in, const int* in_sizes, int n_in,
                              void* d_out, int out_size, void* d_ws, size_t ws_size,
                              hipStream_t stream) {
  const float* q    = (const float*)d_in[0];
  const float* k    = (const float*)d_in[1];
  const float* v    = (const float*)d_in[2];
  const float* cov  = (const float*)d_in[3];
  const float* lam  = (const float*)d_in[4];
  const int*   mask = (const int*)d_in[5];
  float* outO = (float*)d_out;
  float* outA = outO + (size_t)Bdim * Hdim * Sdim * Ddim;

  short* kb = (short*)d_ws;                                  // 4 MB bf16 K
  short* vt = kb + (size_t)Bdim * Hdim * Sdim * Ddim;        // 4 MB bf16 V^T
  short* cm = vt + (size_t)Bdim * Hdim * Sdim * Ddim;        // 16.7 MB bf16 covm
  (void)ws_size;

  cvt_k<<<dim3((Bdim * Hdim * Sdim * Ddim) / (256 * 8)), 256, 0, stream>>>(k, kb);
  tr_v<<<dim3(Bdim * Hdim * (Sdim / 64)), 256, 0, stream>>>(v, vt);
  cvt_cov<<<dim3(Bdim * (Sdim / 16) * 8), 256, 0, stream>>>(cov, mask, cm);

  dim3 grid(Bdim * Hdim * (Sdim / 16));   // 2048 blocks x 512 threads
  fused_attn<<<grid, 512, 0, stream>>>(q, kb, vt, cm, lam, outO, outA);
}